// Round 12
// baseline (164.379 us; speedup 1.0000x reference)
//
#include <hip/hip_runtime.h>
#include <math.h>

#define HH 256
#define WW 256
#define CC 8
#define KK 25
#define ND 9
#define NB 2
#define HW (HH * WW)

typedef int   int4v   __attribute__((ext_vector_type(4)));
typedef float float2v __attribute__((ext_vector_type(2)));

// Raw buffer loads: hardware bounds check vs num_records; negative voffset =
// huge unsigned = OOB -> returns 0. Validated rounds 8-11 (absmax 0.0),
// including the dwordx2 even-shift both-in/both-out property (round 9).
__device__ float llvm_amdgcn_raw_buffer_load_fp32(int4v srsrc, int voffset,
                                                  int soffset, int aux)
    __asm("llvm.amdgcn.raw.buffer.load.f32");
__device__ float2v llvm_amdgcn_raw_buffer_load_v2fp32(int4v srsrc, int voffset,
                                                      int soffset, int aux)
    __asm("llvm.amdgcn.raw.buffer.load.v2f32");

__device__ __forceinline__ int4v make_row_srd(const float* rowp, int yv) {
    int4v srd;
    srd.x = (int)(uintptr_t)rowp;
    srd.y = (int)((uintptr_t)rowp >> 32);
    srd.z = yv ? (WW * 4) : 0;   // num_records: 0 => whole row OOB -> 0
    srd.w = 0x00020000;
    return srd;
}

// One tap group (g, VV): 9 fm taps (2 px wide) + mask pair; consume immediately.
// VV templated so dv, and thus every voffset literal, is compile-time.
template<int VV>
__device__ __forceinline__ void tap_group(int g, int du, int i, int jj4,
    const float* __restrict__ fmb, const float* __restrict__ mb,
    const float* __restrict__ wc,
    float2v& msum, float (&acc0)[ND], float (&acc1)[ND])
{
    const int k = 5 * g + VV;
    constexpr int dv = VV - 2;
    const float2v mk = *(const float2v*)(mb + (size_t)k * HW);
    const float wk = wc[k];
    const float* fpk = fmb + (size_t)k * HW;

    float2v f2[ND];                       // 18 regs of in-flight loads
#pragma unroll
    for (int dd = 0; dd < ND; ++dd) {
        constexpr int NDl = ND;           // (silence unused warn paths)
        const int d  = dd - 4;            // literal under unroll
        const int y  = i - du * d;        // uniform
        const int yv = ((unsigned)y < HH);
        const int yc = min(max(y, 0), HH - 1);
        const int4v srd = make_row_srd(fpk + yc * WW, yv);
        const int sp = -dv * d;           // column shift, literal in [-8,8]
        const int vo = jj4 + sp * 4;      // single base + literal add (no table)
        if ((sp & 1) == 0) {
            f2[dd] = llvm_amdgcn_raw_buffer_load_v2fp32(srd, vo, 0, 0);
        } else {
            f2[dd].x = llvm_amdgcn_raw_buffer_load_fp32(srd, vo, 0, 0);
            f2[dd].y = llvm_amdgcn_raw_buffer_load_fp32(srd, vo + 4, 0, 0);
        }
        (void)NDl;
    }
    msum.x = __fadd_rn(msum.x, mk.x);
    msum.y = __fadd_rn(msum.y, mk.y);
#pragma unroll
    for (int dd = 0; dd < ND; ++dd) {
        const float p0 = __fmul_rn(f2[dd].x, mk.x);
        const float t0 = __fmul_rn(p0, wk);
        acc0[dd] = __fadd_rn(acc0[dd], t0);
        const float p1 = __fmul_rn(f2[dd].y, mk.y);
        const float t1 = __fmul_rn(p1, wk);
        acc1[dd] = __fadd_rn(acc1[dd], t1);
    }
}

__global__ __launch_bounds__(256, 4) void cost_kernel(
    const float* __restrict__ fm,    // [B][C][K][H][W]
    const float* __restrict__ mask,  // [B][K][H][W]
    const float* __restrict__ wgt,   // [C][K]
    float* __restrict__ out)         // [B][C][ND][H][W]
{
#pragma clang fp contract(off)
    const int tid = threadIdx.x;
    const int jj  = (tid & 127) << 1;     // column pair (wave = 128 contiguous cols)
    const int rr  = tid >> 7;             // row within block (0..1)

    // XCD-chunked swizzle over 2048 row-pair blocks.
    const int vb  = blockIdx.x;
    const int nid = (vb & 7) * (NB * CC * HH / 2 / 8) + (vb >> 3);
    const int i = ((nid & 127) << 1) + rr;   // row (uniform per wave)
    const int c = (nid >> 7) & 7;            // channel
    const int b = nid >> 10;                 // batch

    const float* fmb = fm + (size_t)(b * CC + c) * KK * HW;
    const float* mb  = mask + (size_t)b * KK * HW + (size_t)i * WW + jj;
    const float* wc  = wgt + c * KK;
    const int jj4 = jj * 4;

    float acc0[ND], acc1[ND];
#pragma unroll
    for (int dd = 0; dd < ND; ++dd) { acc0[dd] = 0.f; acc1[dd] = 0.f; }
    float2v msum; msum.x = 0.f; msum.y = 0.f;

    // k = 5*g + v ascending (strict numpy order, per-pixel chain unchanged).
    for (int g = 0; g < 5; ++g) {
        const int du = g - 2;
        tap_group<0>(g, du, i, jj4, fmb, mb, wc, msum, acc0, acc1);
        tap_group<1>(g, du, i, jj4, fmb, mb, wc, msum, acc0, acc1);
        tap_group<2>(g, du, i, jj4, fmb, mb, wc, msum, acc0, acc1);
        tap_group<3>(g, du, i, jj4, fmb, mb, wc, msum, acc0, acc1);
        tap_group<4>(g, du, i, jj4, fmb, mb, wc, msum, acc0, acc1);
    }

    const float mavg0 = __fdiv_rn(msum.x, 25.0f);
    const float mavg1 = __fdiv_rn(msum.y, 25.0f);
    float* ob = out + (size_t)(b * CC + c) * ND * HW + (size_t)i * WW + jj;
#pragma unroll
    for (int dd = 0; dd < ND; ++dd) {
        float2v o;
        o.x = floorf(__fdiv_rn(acc0[dd], mavg0));
        o.y = floorf(__fdiv_rn(acc1[dd], mavg1));
        *(float2v*)(ob + (size_t)dd * HW) = o;
    }
}

extern "C" void kernel_launch(void* const* d_in, const int* in_sizes, int n_in,
                              void* d_out, int out_size, void* d_ws, size_t ws_size,
                              hipStream_t stream) {
    const float* fm   = (const float*)d_in[0];
    const float* mask = (const float*)d_in[1];
    const float* wgt  = (const float*)d_in[2];
    float* out = (float*)d_out;

    dim3 grid(NB * CC * HH / 2);  // 2048 blocks: (b, c, row pair), XCD-swizzled
    dim3 block(256);              // 2 rows x 128 threads x 2 px
    cost_kernel<<<grid, block, 0, stream>>>(fm, mask, wgt, out);
}

// Round 13
// 78.680 us; speedup vs baseline: 2.0892x; 2.0892x over previous
//
#include <hip/hip_runtime.h>
#include <math.h>

#define HH 256
#define WW 256
#define CC 8
#define KK 25
#define ND 9
#define NB 2
#define HW (HH * WW)

typedef int   int4v   __attribute__((ext_vector_type(4)));
typedef float float2v __attribute__((ext_vector_type(2)));

// Raw buffer loads: per-dword hardware bounds check vs num_records; negative
// voffset = huge unsigned = OOB -> returns 0 (validated rounds 8-12, absmax 0.0).
__device__ float llvm_amdgcn_raw_buffer_load_fp32(int4v srsrc, int voffset,
                                                  int soffset, int aux)
    __asm("llvm.amdgcn.raw.buffer.load.f32");
__device__ float2v llvm_amdgcn_raw_buffer_load_v2fp32(int4v srsrc, int voffset,
                                                      int soffset, int aux)
    __asm("llvm.amdgcn.raw.buffer.load.v2f32");

// HALF 0: disparities d=-4..0 (dd 0..4).  HALF 1: d=+1..+4 (dd 5..8).
// Scalar float arrays only (no ext-vector arrays -> no scratch, r12 lesson).
template<int HALF>
__device__ __forceinline__ void compute_half(
    int i, int jj, const float* __restrict__ fmb, const float* __restrict__ mb,
    const float* __restrict__ wc, float* __restrict__ ob)
{
    constexpr int DD0 = HALF ? 5 : 0;
    constexpr int NDD = HALF ? 4 : 5;
    const int jj4 = jj * 4;

    float acc0[NDD], acc1[NDD];
#pragma unroll
    for (int q = 0; q < NDD; ++q) { acc0[q] = 0.f; acc1[q] = 0.f; }
    float ms0 = 0.f, ms1 = 0.f;

    // k = 5*g + v ascending (strict numpy order; per-pixel chain unchanged).
    for (int g = 0; g < 5; ++g) {
        const int du = g - 2;
#pragma unroll
        for (int v = 0; v < 5; ++v) {
            const int k  = 5 * g + v;
            const int dv = v - 2;
            const float2v mk = *(const float2v*)(mb + (size_t)k * HW);
            const float wk = wc[k];
            const float* fpk = fmb + (size_t)k * HW;

            float fx[NDD], fy[NDD];              // batch of independent loads
#pragma unroll
            for (int q = 0; q < NDD; ++q) {
                const int d  = DD0 + q - 4;      // literal under unroll
                const int y  = i - du * d;       // uniform
                const int yv = ((unsigned)y < HH);
                const int yc = min(max(y, 0), HH - 1);
                const float* rowp = fpk + yc * WW;   // uniform -> SGPRs
                int4v srd;
                srd.x = (int)(uintptr_t)rowp;
                srd.y = (int)((uintptr_t)rowp >> 32);
                srd.z = yv ? (WW * 4) : 0;       // 0 => whole row OOB -> 0
                srd.w = 0x00020000;
                const int sp = -dv * d;          // column shift, literal
                const int vo = jj4 + sp * 4;
                if ((sp & 1) == 0) {
                    // even shift: dword pair is both-in or both-out -> 1 load
                    const float2v t =
                        llvm_amdgcn_raw_buffer_load_v2fp32(srd, vo, 0, 0);
                    fx[q] = t.x; fy[q] = t.y;
                } else {
                    fx[q] = llvm_amdgcn_raw_buffer_load_fp32(srd, vo, 0, 0);
                    fy[q] = llvm_amdgcn_raw_buffer_load_fp32(srd, vo + 4, 0, 0);
                }
            }
            ms0 = __fadd_rn(ms0, mk.x);
            ms1 = __fadd_rn(ms1, mk.y);
#pragma unroll
            for (int q = 0; q < NDD; ++q) {
                const float p0 = __fmul_rn(fx[q], mk.x);   // shifted * mask
                const float t0 = __fmul_rn(p0, wk);        // * weight
                acc0[q] = __fadd_rn(acc0[q], t0);          // sequential k-sum
                const float p1 = __fmul_rn(fy[q], mk.y);
                const float t1 = __fmul_rn(p1, wk);
                acc1[q] = __fadd_rn(acc1[q], t1);
            }
        }
    }

    const float mavg0 = __fdiv_rn(ms0, 25.0f);
    const float mavg1 = __fdiv_rn(ms1, 25.0f);
#pragma unroll
    for (int q = 0; q < NDD; ++q) {
        const int dd = DD0 + q;
        float2v o;
        o.x = floorf(__fdiv_rn(acc0[q], mavg0));
        o.y = floorf(__fdiv_rn(acc1[q], mavg1));
        *(float2v*)(ob + (size_t)dd * HW) = o;
    }
}

__global__ __launch_bounds__(256) void cost_kernel(
    const float* __restrict__ fm,    // [B][C][K][H][W]
    const float* __restrict__ mask,  // [B][K][H][W]
    const float* __restrict__ wgt,   // [C][K]
    float* __restrict__ out)         // [B][C][ND][H][W]
{
#pragma clang fp contract(off)
    const int tid  = threadIdx.x;
    const int half = tid >> 7;            // wave-uniform (waves 0-1: A, 2-3: B)
    const int jj   = (tid & 127) << 1;    // column pair; wave = 128 contiguous cols

    // XCD-chunked swizzle (round 8): each XCD owns a contiguous id range.
    const int vb = blockIdx.x;
    const int nid = (vb & 7) * (NB * CC * HH / 8) + (vb >> 3);
    const int i = nid & 255;              // row (uniform)
    const int c = (nid >> 8) & 7;         // channel
    const int b = nid >> 11;              // batch

    const float* fmb = fm + (size_t)(b * CC + c) * KK * HW;
    const float* mb  = mask + (size_t)b * KK * HW + (size_t)i * WW + jj;
    const float* wc  = wgt + c * KK;
    float* ob = out + (size_t)(b * CC + c) * ND * HW + (size_t)i * WW + jj;

    if (half == 0) compute_half<0>(i, jj, fmb, mb, wc, ob);
    else           compute_half<1>(i, jj, fmb, mb, wc, ob);
}

extern "C" void kernel_launch(void* const* d_in, const int* in_sizes, int n_in,
                              void* d_out, int out_size, void* d_ws, size_t ws_size,
                              hipStream_t stream) {
    const float* fm   = (const float*)d_in[0];
    const float* mask = (const float*)d_in[1];
    const float* wgt  = (const float*)d_in[2];
    float* out = (float*)d_out;

    dim3 grid(NB * CC * HH);   // 4096 blocks: (b, c, row), XCD-swizzled
    dim3 block(256);           // halves: tid<128 -> dd 0..4, else dd 5..8; 2 px/thread
    cost_kernel<<<grid, block, 0, stream>>>(fm, mask, wgt, out);
}